// Round 7
// baseline (520.205 us; speedup 1.0000x reference)
//
#include <hip/hip_runtime.h>

#define GROUPS 32
#define CPG    16
#define C_DIM  512
#define HW     1024
#define B_DIM  32

typedef __attribute__((ext_vector_type(8))) short bf16x8;
typedef __attribute__((ext_vector_type(4))) float f32x4;
typedef __attribute__((ext_vector_type(8))) unsigned short u16x8;

__device__ inline unsigned short f2bf(float f) {
  unsigned u = __builtin_bit_cast(unsigned, f);
  u += 0x7fff + ((u >> 16) & 1);   // RNE
  return (unsigned short)(u >> 16);
}
__device__ inline float bf2f(unsigned short s) {
  return __builtin_bit_cast(float, ((unsigned)s) << 16);
}

__device__ inline void mfma16(f32x4& d, bf16x8 a, bf16x8 b) {
  asm("v_mfma_f32_16x16x32_bf16 %0, %1, %2, %0" : "+v"(d) : "v"(a), "v"(b));
}

// m97-style linear staging: 128 rows x 64 cols bf16, 4 waves. Proven round-4.
__device__ inline void stage128x64(const unsigned short* g0, size_t rowStride,
                                   unsigned short* lds, int wave, int lane) {
  int r  = lane >> 3;
  int k8 = (lane & 7) * 8;
#pragma unroll
  for (int i = 0; i < 4; ++i) {
    const unsigned short* g = g0 + (size_t)(wave * 32 + i * 8 + r) * rowStride + k8;
    unsigned short* l = lds + (wave * 32 + i * 8) * 64;
    __builtin_amdgcn_global_load_lds((const __attribute__((address_space(1))) void*)g,
                                     (__attribute__((address_space(3))) void*)l, 16, 0, 0);
  }
}

// 128x128 tile: 4 waves (2x2), each 64x64 via 4x4 16x16x32 frags. LDS [row][64].
__device__ inline void mfma_tile64(const unsigned short* As, const unsigned short* Bs,
                                   f32x4 acc[4][4], int lane, int wm, int wn) {
  int ar = (wm * 64 + (lane & 15)) * 64 + ((lane >> 4) << 3);
  int br = (wn * 64 + (lane & 15)) * 64 + ((lane >> 4) << 3);
#pragma unroll
  for (int kk = 0; kk < 64; kk += 32) {
    bf16x8 a[4], b[4];
#pragma unroll
    for (int mi = 0; mi < 4; ++mi) a[mi] = *(const bf16x8*)&As[ar + mi * 16 * 64 + kk];
#pragma unroll
    for (int ni = 0; ni < 4; ++ni) b[ni] = *(const bf16x8*)&Bs[br + ni * 16 * 64 + kk];
#pragma unroll
    for (int mi = 0; mi < 4; ++mi)
#pragma unroll
      for (int ni = 0; ni < 4; ++ni) mfma16(acc[mi][ni], a[mi], b[ni]);
  }
}

// ---------------- kernel 1: GroupNorm stats ----------------
__global__ __launch_bounds__(256) void gn_stats_k(const float* __restrict__ x,
                                                  float* __restrict__ mean,
                                                  float* __restrict__ rstd) {
  int blk = blockIdx.x;
  const float4* p = (const float4*)(x + (size_t)blk * (CPG * HW));
  float s = 0.f, ss = 0.f;
  for (int i = threadIdx.x; i < CPG * HW / 4; i += 256) {
    float4 v = p[i];
    s  += v.x + v.y + v.z + v.w;
    ss += v.x * v.x + v.y * v.y + v.z * v.z + v.w * v.w;
  }
#pragma unroll
  for (int off = 32; off > 0; off >>= 1) {
    s  += __shfl_xor(s, off);
    ss += __shfl_xor(ss, off);
  }
  __shared__ float sm[8];
  int wave = threadIdx.x >> 6, lane = threadIdx.x & 63;
  if (lane == 0) { sm[wave] = s; sm[wave + 4] = ss; }
  __syncthreads();
  if (threadIdx.x == 0) {
    float S  = sm[0] + sm[1] + sm[2] + sm[3];
    float SS = sm[4] + sm[5] + sm[6] + sm[7];
    float mu  = S * (1.f / (CPG * HW));
    float var = SS * (1.f / (CPG * HW)) - mu * mu;
    mean[blk] = mu;
    rstd[blk] = rsqrtf(var + 1e-5f);
  }
}

// ---------------- kernel 2: weights -> bf16 (attn scale folded into q,k) ----------------
__global__ __launch_bounds__(256) void prep_k(const float* __restrict__ qkv_w,
                                              const float* __restrict__ qkv_b,
                                              const float* __restrict__ proj_w,
                                              unsigned short* __restrict__ wq_bf,
                                              unsigned short* __restrict__ pw_bf,
                                              float* __restrict__ b_s) {
  const float SC = 0.21022410381342863f;  // 512^-0.25
  int t = blockIdx.x * 256 + threadIdx.x;
  for (int i = t; i < 1536 * 512 / 4; i += gridDim.x * 256) {
    float4 w = *(const float4*)&qkv_w[i * 4];
    float sc = (i * 4 < 1024 * 512) ? SC : 1.f;
    ushort4 o;
    o.x = f2bf(w.x * sc); o.y = f2bf(w.y * sc); o.z = f2bf(w.z * sc); o.w = f2bf(w.w * sc);
    *(ushort4*)&wq_bf[i * 4] = o;
  }
  for (int i = t; i < 512 * 512 / 4; i += gridDim.x * 256) {
    float4 w = *(const float4*)&proj_w[i * 4];
    ushort4 o;
    o.x = f2bf(w.x); o.y = f2bf(w.y); o.z = f2bf(w.z); o.w = f2bf(w.w);
    *(ushort4*)&pw_bf[i * 4] = o;
  }
  if (t < 1536) b_s[t] = qkv_b[t] * (t < 1024 ? SC : 1.f);
}

// ---------------- kernel 3: GN-normalize + transpose -> hn_t[b][p][c] bf16 ----------------
__global__ __launch_bounds__(256) void gn_apply_t_k(const float* __restrict__ x,
                                                    const float* __restrict__ gamma,
                                                    const float* __restrict__ beta,
                                                    const float* __restrict__ mean,
                                                    const float* __restrict__ rstd,
                                                    unsigned short* __restrict__ hn_t) {
  __shared__ unsigned short Ls[64 * 68];
  int b = blockIdx.z, p0 = blockIdx.x * 64, c0 = blockIdx.y * 64;
  int tid = threadIdx.x;
  int c_loc = tid >> 4, p4 = (tid & 15) * 4;
#pragma unroll
  for (int cc = 0; cc < 4; ++cc) {
    int c = c_loc + cc * 16;
    int cg = c0 + c;
    float rs = rstd[b * GROUPS + (cg >> 4)];
    float ga = gamma[cg] * rs;
    float be = beta[cg] - mean[b * GROUPS + (cg >> 4)] * ga;
    float4 x4 = *(const float4*)&x[((size_t)b * C_DIM + cg) * HW + p0 + p4];
    ushort4 o;
    o.x = f2bf(x4.x * ga + be); o.y = f2bf(x4.y * ga + be);
    o.z = f2bf(x4.z * ga + be); o.w = f2bf(x4.w * ga + be);
    *(ushort4*)&Ls[c * 68 + p4] = o;
  }
  __syncthreads();
#pragma unroll
  for (int pass = 0; pass < 2; ++pass) {
    int cid = tid + pass * 256;
    int p = cid >> 3, c8 = cid & 7;
    u16x8 o;
#pragma unroll
    for (int u = 0; u < 8; ++u) o[u] = Ls[(c8 * 8 + u) * 68 + p];
    *(u16x8*)&hn_t[((size_t)b * HW + p0 + p) * C_DIM + c0 + c8 * 8] = o;
  }
}

// ---------------- kernel 4: QKV GEMM (round-4 core + T1 XCD chunking) ----------------
__global__ __launch_bounds__(256) void qkv_gemm_k(
    const unsigned short* __restrict__ wq_bf, const unsigned short* __restrict__ hn_t,
    const float* __restrict__ b_s, unsigned short* __restrict__ q_t,
    unsigned short* __restrict__ k_t, unsigned short* __restrict__ vx) {
  __shared__ __align__(16) unsigned short As[128 * 64];
  __shared__ __align__(16) unsigned short Bs[128 * 64];
  // T1: 3072 blocks -> 8 chunks of 384; within chunk: batch-major, bx fastest
  int lin = blockIdx.x;
  int tgt = (lin & 7) * 384 + (lin >> 3);
  int b = tgt / 96, rem = tgt % 96, by = rem / 12, bx = rem % 12;
  int o0 = bx * 128, p0 = by * 128;
  int tid = threadIdx.x, lane = tid & 63, wave = tid >> 6, wm = wave >> 1, wn = wave & 1;
  f32x4 acc[4][4] = {};
  const unsigned short* hb = hn_t + (size_t)b * HW * C_DIM;
  for (int kt = 0; kt < C_DIM; kt += 64) {
    __syncthreads();
    stage128x64(wq_bf + (size_t)o0 * C_DIM + kt, C_DIM, As, wave, lane);
    stage128x64(hb + (size_t)p0 * C_DIM + kt, C_DIM, Bs, wave, lane);
    __syncthreads();
    mfma_tile64(As, Bs, acc, lane, wm, wn);
  }
#pragma unroll
  for (int mi = 0; mi < 4; ++mi) {
    int obase = o0 + wm * 64 + mi * 16 + ((lane >> 4) << 2);
    float4 bias = *(const float4*)&b_s[obase];
#pragma unroll
    for (int ni = 0; ni < 4; ++ni) {
      int p = p0 + wn * 64 + ni * 16 + (lane & 15);
      if (o0 < 512) {
        ushort4 o;
        o.x = f2bf(acc[mi][ni][0] + bias.x); o.y = f2bf(acc[mi][ni][1] + bias.y);
        o.z = f2bf(acc[mi][ni][2] + bias.z); o.w = f2bf(acc[mi][ni][3] + bias.w);
        *(ushort4*)&q_t[((size_t)b * HW + p) * C_DIM + obase] = o;
      } else if (o0 < 1024) {
        ushort4 o;
        o.x = f2bf(acc[mi][ni][0] + bias.x); o.y = f2bf(acc[mi][ni][1] + bias.y);
        o.z = f2bf(acc[mi][ni][2] + bias.z); o.w = f2bf(acc[mi][ni][3] + bias.w);
        *(ushort4*)&k_t[((size_t)b * HW + p) * C_DIM + obase - 512] = o;
      } else {
        float bb[4] = {bias.x, bias.y, bias.z, bias.w};
#pragma unroll
        for (int r = 0; r < 4; ++r)
          vx[((size_t)b * C_DIM + obase - 1024 + r) * HW + p] = f2bf(acc[mi][ni][r] + bb[r]);
      }
    }
  }
}

// ---------------- kernel 5: fused flash attention (qk + softmax + pv) ----------------
// Block: 128 q-rows x 1 batch. 8 waves; wave w owns S-strip rows [w*16,w*16+16)
// and O-strip [128i][c in w*64..w*64+64). q in regs; K[64][512], V[512][64],
// P[128][64] in LDS. Online softmax. K/V prefetch hidden: issue right after the
// barrier that frees the buffer; the next barrier's vmcnt drain lands it free.
// All LDS reads use (row&7) chunk-XOR (measured 0 conflicts, round 5).
#define FK_K 0
#define FK_V 32768
#define FK_P 65536
#define FK_SC 73728   // float[128] at shorts offset (byte 147456)
#define FK_LI 73984   // float[128]
__global__ __launch_bounds__(512, 2) void flash_k(const unsigned short* __restrict__ q_t,
                                                  const unsigned short* __restrict__ k_t,
                                                  const unsigned short* __restrict__ vx,
                                                  unsigned short* __restrict__ ha_t) {
  extern __shared__ unsigned short lds[];
  unsigned short* k_lds = lds + FK_K;
  unsigned short* v_lds = lds + FK_V;
  unsigned short* p_lds = lds + FK_P;
  float* sc_lds = (float*)(lds + FK_SC);
  float* li_lds = (float*)(lds + FK_LI);

  int lin = blockIdx.x;                       // 256 blocks -> 1/CU
  int tgt = (lin & 7) * 32 + (lin >> 3);      // T1: 4 batches per XCD chunk
  int b = tgt >> 3, itile = tgt & 7;
  int i0 = itile * 128;
  int tid = threadIdx.x, lane = tid & 63, w = tid >> 6;
  int L4 = lane & 15, hi = lane >> 4;

  // ---- q fragments in registers: rows w*16+L4, all c ----
  bf16x8 qf[16];
  {
    const unsigned short* qrow = q_t + ((size_t)b * HW + i0 + w * 16 + L4) * C_DIM + hi * 8;
#pragma unroll
    for (int cc = 0; cc < 16; ++cc) qf[cc] = *(const bf16x8*)&qrow[cc * 32];
  }

  f32x4 acc[8][4] = {};
  float m_run[4] = {-3.0e38f, -3.0e38f, -3.0e38f, -3.0e38f};
  float l_run[4] = {0.f, 0.f, 0.f, 0.f};

  const unsigned short* kb = k_t + (size_t)b * HW * C_DIM;
  const unsigned short* vb0 = vx + (size_t)b * C_DIM * HW;

  // stage K-tile t: rows j=rr*8+w (full 1024B row per wave), chunk^=(j&7) low3
  auto stageK = [&](int t) {
#pragma unroll
    for (int rr = 0; rr < 8; ++rr) {
      int j = rr * 8 + w;
      const unsigned short* g = kb + (size_t)(t * 64 + j) * C_DIM + ((lane ^ (j & 7)) * 8);
      unsigned short* l = k_lds + j * 512;
      __builtin_amdgcn_global_load_lds((const __attribute__((address_space(1))) void*)g,
                                       (__attribute__((address_space(3))) void*)l, 16, 0, 0);
    }
  };
  // stage V-tile t: rows c=rr*64+w*8+(lane>>3), chunk=(lane&7)^(c&7)
  auto stageV = [&](int t) {
#pragma unroll
    for (int rr = 0; rr < 8; ++rr) {
      int c = rr * 64 + w * 8 + (lane >> 3);
      const unsigned short* g = vb0 + (size_t)c * HW + t * 64 + (((lane & 7) ^ (lane >> 3)) * 8);
      unsigned short* l = v_lds + (rr * 64 + w * 8) * 64;
      __builtin_amdgcn_global_load_lds((const __attribute__((address_space(1))) void*)g,
                                       (__attribute__((address_space(3))) void*)l, 16, 0, 0);
    }
  };

  stageK(0);
  stageV(0);
  __syncthreads();

  for (int t = 0; t < 16; ++t) {
    // ---- S-phase: s[ni] = q x k, rows w*16+.., cols j=ni*16+L4 of this tile ----
    f32x4 s[4] = {};
#pragma unroll
    for (int cc = 0; cc < 16; ++cc) {
      bf16x8 kf[4];
#pragma unroll
      for (int ni = 0; ni < 4; ++ni) {
        int j = ni * 16 + L4;
        int jc = (cc * 4 + hi) ^ (j & 7);
        kf[ni] = *(const bf16x8*)&k_lds[j * 512 + jc * 8];
      }
#pragma unroll
      for (int ni = 0; ni < 4; ++ni) mfma16(s[ni], qf[cc], kf[ni]);
    }
    // ---- online softmax on 16-row strip (rows i_loc = w*16 + hi*4 + r) ----
    float sc_f[4];
#pragma unroll
    for (int r = 0; r < 4; ++r) {
      float rmax = fmaxf(fmaxf(s[0][r], s[1][r]), fmaxf(s[2][r], s[3][r]));
#pragma unroll
      for (int mk = 1; mk < 16; mk <<= 1) rmax = fmaxf(rmax, __shfl_xor(rmax, mk));
      float mnew = fmaxf(m_run[r], rmax);
      sc_f[r] = __expf(m_run[r] - mnew);
      float rsum = 0.f;
      int i_loc = w * 16 + hi * 4 + r;
      int sw = (i_loc & 7) << 3;
#pragma unroll
      for (int ni = 0; ni < 4; ++ni) {
        float pv = __expf(s[ni][r] - mnew);
        rsum += pv;
        p_lds[i_loc * 64 + ((ni * 16 + L4) ^ sw)] = f2bf(pv);
      }
#pragma unroll
      for (int mk = 1; mk < 16; mk <<= 1) rsum += __shfl_xor(rsum, mk);
      l_run[r] = l_run[r] * sc_f[r] + rsum;
      m_run[r] = mnew;
      if (L4 == 0) sc_lds[i_loc] = sc_f[r];
    }
    __syncthreads();                 // P+scale ready; K reads done; V(t) landed
    if (t < 15) stageK(t + 1);       // into freed K buffer, lands during PV
    // ---- PV: rescale acc, then acc += P x V ----
#pragma unroll
    for (int mi = 0; mi < 8; ++mi) {
      f32x4 scv = *(const f32x4*)&sc_lds[mi * 16 + hi * 4];
#pragma unroll
      for (int ni = 0; ni < 4; ++ni) acc[mi][ni] *= scv;
    }
#pragma unroll
    for (int kk = 0; kk < 2; ++kk) {
      bf16x8 vf[4];
#pragma unroll
      for (int ni = 0; ni < 4; ++ni) {
        int c = w * 64 + ni * 16 + L4;
        int jc = (hi + kk * 4) ^ (c & 7);
        vf[ni] = *(const bf16x8*)&v_lds[(c & 511) * 64 + jc * 8];
      }
#pragma unroll
      for (int mi = 0; mi < 8; ++mi) {
        int ir = mi * 16 + L4;
        int jc = (hi + kk * 4) ^ (ir & 7);
        bf16x8 pa = *(const bf16x8*)&p_lds[ir * 64 + jc * 8];
#pragma unroll
        for (int ni = 0; ni < 4; ++ni) mfma16(acc[mi][ni], pa, vf[ni]);
      }
    }
    __syncthreads();                 // V+P reads done; K(t+1) landed
    if (t < 15) stageV(t + 1);       // into freed V buffer, lands during S-phase
  }
  // ---- epilogue: O /= l, write ha_t[b][i][c] ----
#pragma unroll
  for (int r = 0; r < 4; ++r)
    if (L4 == 0) li_lds[w * 16 + hi * 4 + r] = 1.0f / l_run[r];
  __syncthreads();
#pragma unroll
  for (int mi = 0; mi < 8; ++mi) {
    f32x4 li = *(const f32x4*)&li_lds[mi * 16 + hi * 4];
    size_t gi = (size_t)b * HW + i0 + mi * 16 + hi * 4;
#pragma unroll
    for (int ni = 0; ni < 4; ++ni) {
      int c = w * 64 + ni * 16 + L4;
#pragma unroll
      for (int r = 0; r < 4; ++r)
        ha_t[(gi + r) * C_DIM + c] = f2bf(acc[mi][ni][r] * li[r]);
    }
  }
}

// ---------------- kernel 6: out = x + proj_w @ O + proj_b (round-4 core + T1) ----------------
__global__ __launch_bounds__(256) void proj_gemm_k(const float* __restrict__ x,
                                                   const unsigned short* __restrict__ ha_t,
                                                   const unsigned short* __restrict__ pw_bf,
                                                   const float* __restrict__ proj_b,
                                                   float* __restrict__ out) {
  __shared__ __align__(16) unsigned short As[128 * 64];
  __shared__ __align__(16) unsigned short Bs[128 * 64];
  int lin = blockIdx.x;
  int tgt = (lin & 7) * 128 + (lin >> 3);
  int b = tgt / 32, rem = tgt % 32, by = rem / 4, bx = rem % 4;
  int o0 = bx * 128, p0 = by * 128;
  int tid = threadIdx.x, lane = tid & 63, wave = tid >> 6, wm = wave >> 1, wn = wave & 1;
  f32x4 acc[4][4] = {};
  const unsigned short* hb = ha_t + (size_t)b * HW * C_DIM;
  for (int kt = 0; kt < C_DIM; kt += 64) {
    __syncthreads();
    stage128x64(pw_bf + (size_t)o0 * C_DIM + kt, C_DIM, As, wave, lane);
    stage128x64(hb + (size_t)p0 * C_DIM + kt, C_DIM, Bs, wave, lane);
    __syncthreads();
    mfma_tile64(As, Bs, acc, lane, wm, wn);
  }
  const float* xb = x + (size_t)b * C_DIM * HW;
  float* ob = out + (size_t)b * C_DIM * HW;
#pragma unroll
  for (int mi = 0; mi < 4; ++mi)
#pragma unroll
    for (int ni = 0; ni < 4; ++ni) {
      int p = p0 + wn * 64 + ni * 16 + (lane & 15);
#pragma unroll
      for (int r = 0; r < 4; ++r) {
        int o = o0 + wm * 64 + mi * 16 + ((lane >> 4) << 2) + r;
        size_t idx = (size_t)o * HW + p;
        ob[idx] = xb[idx] + acc[mi][ni][r] + proj_b[o];
      }
    }
}

extern "C" void kernel_launch(void* const* d_in, const int* in_sizes, int n_in,
                              void* d_out, int out_size, void* d_ws, size_t ws_size,
                              hipStream_t stream) {
  const float* x      = (const float*)d_in[0];
  const float* gamma  = (const float*)d_in[1];
  const float* beta   = (const float*)d_in[2];
  const float* qkv_w  = (const float*)d_in[3];
  const float* qkv_b  = (const float*)d_in[4];
  const float* proj_w = (const float*)d_in[5];
  const float* proj_b = (const float*)d_in[6];
  float* out = (float*)d_out;

  // ws: header 4MB | v 32MB | ha_t 32MB | hn_t 32MB  (no S buffer: flash-fused)
  // q_t/k_t live in d_out (dead before proj writes out).
  char* ws = (char*)d_ws;
  float* mean = (float*)ws;
  float* rstd = (float*)(ws + 4096);
  float* b_s  = (float*)(ws + 8192);
  unsigned short* pw_bf = (unsigned short*)(ws + 16384);
  unsigned short* wq_bf = (unsigned short*)(ws + 16384 + 512 * 512 * 2);
  unsigned short* vx   = (unsigned short*)(ws + ((size_t)4 << 20));
  unsigned short* ha_t = (unsigned short*)(ws + ((size_t)36 << 20));
  unsigned short* hn_t = (unsigned short*)(ws + ((size_t)68 << 20));
  unsigned short* q_t  = (unsigned short*)d_out;
  unsigned short* k_t  = q_t + (size_t)B_DIM * HW * C_DIM;

  const int FSH = 148480;  // 145KB dynamic LDS for flash_k
  hipFuncSetAttribute((const void*)flash_k, hipFuncAttributeMaxDynamicSharedMemorySize, FSH);

  gn_stats_k<<<dim3(B_DIM * GROUPS), dim3(256), 0, stream>>>(x, mean, rstd);
  prep_k<<<dim3(512), dim3(256), 0, stream>>>(qkv_w, qkv_b, proj_w, wq_bf, pw_bf, b_s);
  gn_apply_t_k<<<dim3(16, 8, B_DIM), dim3(256), 0, stream>>>(x, gamma, beta, mean, rstd, hn_t);
  qkv_gemm_k<<<dim3(3072), dim3(256), 0, stream>>>(wq_bf, hn_t, b_s, q_t, k_t, vx);
  flash_k<<<dim3(256), dim3(512), FSH, stream>>>(q_t, k_t, vx, ha_t);
  proj_gemm_k<<<dim3(1024), dim3(256), 0, stream>>>(x, ha_t, pw_bf, proj_b, out);
}